// Round 1
// baseline (2037.578 us; speedup 1.0000x reference)
//
#include <hip/hip_runtime.h>
#include <hip/hip_bf16.h>

#define N_F 512
#define N_C 1000
#define BM 128
#define BK 64
#define LDK (BK + 8)          // +8 bf16 pad -> row stride 144 B, kills LDS bank conflicts
#define MARGIN 0.0625f        // bf16-logit error bound is ~0.01 worst case; 39 sigma

using short8  = __attribute__((ext_vector_type(8))) short;
using floatx4 = __attribute__((ext_vector_type(4))) float;

__device__ __forceinline__ unsigned short f2bf(float f) {
    unsigned u = __float_as_uint(f);
    unsigned r = u + 0x7FFFu + ((u >> 16) & 1u);   // RNE to bf16
    return (unsigned short)(r >> 16);
}
// monotone float->uint key so LDS atomicMax works for negative floats
__device__ __forceinline__ unsigned fkey(float f) {
    unsigned u = __float_as_uint(f);
    return (u & 0x80000000u) ? ~u : (u | 0x80000000u);
}
__device__ __forceinline__ float kinv(unsigned k) {
    unsigned u = (k & 0x80000000u) ? (k & 0x7FFFFFFFu) : ~k;
    return __uint_as_float(u);
}

// ---------------- Phase 1: bf16 MFMA GEMM + running argmax/candidates + att_out ----
__global__ __launch_bounds__(256, 2) void gemm_argmax_kernel(
    const float* __restrict__ x, const float* __restrict__ W,
    const float* __restrict__ b, float* __restrict__ att_out,
    int* __restrict__ candG)
{
    __shared__ unsigned short As[BM][LDK];
    __shared__ unsigned short Bs[BM][LDK];
    __shared__ unsigned runmaxkey[BM];
    __shared__ int candCnt[BM];
    __shared__ int candLds[BM][7];

    const int tid  = threadIdx.x;
    const int rowBase = blockIdx.x * BM;
    const int lane = tid & 63;
    const int w    = tid >> 6;
    const int wm   = (w >> 1) * 64;   // wave row offset
    const int wn   = (w & 1) * 64;    // wave col offset
    const int quad = lane >> 4;
    const int l16  = lane & 15;

    if (tid < BM) { runmaxkey[tid] = 0u; candCnt[tid] = 0; }

    const int ldRow = tid >> 4;        // 0..15
    const int ldCol = (tid & 15) * 4;  // 0..60

    for (int ct = 0; ct < 8; ++ct) {
        floatx4 acc[4][4];
        #pragma unroll
        for (int mt = 0; mt < 4; ++mt)
            #pragma unroll
            for (int nt = 0; nt < 4; ++nt)
                acc[mt][nt] = (floatx4){0.f, 0.f, 0.f, 0.f};

        const int ctBase = ct * 128;

        for (int k0 = 0; k0 < N_F; k0 += BK) {
            __syncthreads();
            // stage A (x) fp32 -> bf16 ; fuse att_out = 0.9*x on the first class tile
            #pragma unroll
            for (int p = 0; p < 8; ++p) {
                const int r = p * 16 + ldRow;
                const size_t gi = (size_t)(rowBase + r) * N_F + k0 + ldCol;
                const float4 a = *(const float4*)&x[gi];
                if (ct == 0) {
                    float4 o; o.x = 0.9f*a.x; o.y = 0.9f*a.y; o.z = 0.9f*a.z; o.w = 0.9f*a.w;
                    *(float4*)&att_out[gi] = o;
                }
                ushort4 s; s.x = f2bf(a.x); s.y = f2bf(a.y); s.z = f2bf(a.z); s.w = f2bf(a.w);
                *(ushort4*)&As[r][ldCol] = s;
            }
            // stage B (W rows = classes); classes >= 1000 get zeros (masked later anyway)
            #pragma unroll
            for (int p = 0; p < 8; ++p) {
                const int r = p * 16 + ldRow;
                const int c = ctBase + r;
                float4 a;
                if (c < N_C) a = *(const float4*)&W[(size_t)c * N_F + k0 + ldCol];
                else { a.x = a.y = a.z = a.w = 0.f; }
                ushort4 s; s.x = f2bf(a.x); s.y = f2bf(a.y); s.z = f2bf(a.z); s.w = f2bf(a.w);
                *(ushort4*)&Bs[r][ldCol] = s;
            }
            __syncthreads();
            #pragma unroll
            for (int chunk = 0; chunk < 2; ++chunk) {
                const int koff = chunk * 32 + quad * 8;
                short8 af[4], bf[4];
                #pragma unroll
                for (int mt = 0; mt < 4; ++mt)
                    af[mt] = *(const short8*)&As[wm + mt * 16 + l16][koff];
                #pragma unroll
                for (int nt = 0; nt < 4; ++nt)
                    bf[nt] = *(const short8*)&Bs[wn + nt * 16 + l16][koff];
                #pragma unroll
                for (int mt = 0; mt < 4; ++mt)
                    #pragma unroll
                    for (int nt = 0; nt < 4; ++nt)
                        acc[mt][nt] = __builtin_amdgcn_mfma_f32_16x16x32_bf16(
                            af[mt], bf[nt], acc[mt][nt], 0, 0, 0);
            }
        }

        // ---- epilogue for this class tile: running max, then candidate admission ----
        float bv[4]; bool valid[4]; int cls[4];
        #pragma unroll
        for (int nt = 0; nt < 4; ++nt) {
            const int c = ctBase + wn + nt * 16 + l16;
            cls[nt] = c; valid[nt] = (c < N_C);
            bv[nt]  = valid[nt] ? b[c] : 0.f;
        }
        #pragma unroll
        for (int mt = 0; mt < 4; ++mt) {
            #pragma unroll
            for (int i = 0; i < 4; ++i) {
                float m = -3e38f;
                #pragma unroll
                for (int nt = 0; nt < 4; ++nt) {
                    const float v = valid[nt] ? (acc[mt][nt][i] + bv[nt]) : -3e38f;
                    m = fmaxf(m, v);
                }
                m = fmaxf(m, __shfl_xor(m, 1, 64));
                m = fmaxf(m, __shfl_xor(m, 2, 64));
                m = fmaxf(m, __shfl_xor(m, 4, 64));
                m = fmaxf(m, __shfl_xor(m, 8, 64));
                if (l16 == 0) {
                    const int r = wm + mt * 16 + quad * 4 + i;
                    atomicMax(&runmaxkey[r], fkey(m));
                }
            }
        }
        __syncthreads();
        #pragma unroll
        for (int mt = 0; mt < 4; ++mt) {
            #pragma unroll
            for (int i = 0; i < 4; ++i) {
                const int r = wm + mt * 16 + quad * 4 + i;
                const float thresh = kinv(runmaxkey[r]) - MARGIN;
                #pragma unroll
                for (int nt = 0; nt < 4; ++nt) {
                    if (valid[nt]) {
                        const float v = acc[mt][nt][i] + bv[nt];
                        if (v > thresh) {
                            const int s = atomicAdd(&candCnt[r], 1);
                            if (s < 7) candLds[r][s] = cls[nt];
                        }
                    }
                }
            }
        }
    }

    __syncthreads();
    if (tid < BM) {
        const int R = rowBase + tid;
        const int cnt = candCnt[tid];
        candG[(size_t)R * 8] = cnt;
        const int m = cnt < 7 ? cnt : 7;
        for (int s = 0; s < m; ++s) candG[(size_t)R * 8 + 1 + s] = candLds[tid][s];
    }
}

// ---------------- Phase 1.5: resolve label per row (fp64 recheck of candidates) ----
__global__ __launch_bounds__(256) void label_kernel(
    const float* __restrict__ x, const float* __restrict__ W,
    const float* __restrict__ b, const int* __restrict__ candG,
    int* __restrict__ labels)
{
    const int row  = blockIdx.x * 4 + (threadIdx.x >> 6);
    const int lane = threadIdx.x & 63;
    const int cnt  = candG[(size_t)row * 8];
    if (cnt == 1) {                       // ~93% of rows: unique candidate, provably argmax
        if (lane == 0) labels[row] = candG[(size_t)row * 8 + 1];
        return;
    }
    const float* xr = x + (size_t)row * N_F;
    const float4 x0 = *(const float4*)&xr[lane * 8];
    const float4 x1 = *(const float4*)&xr[lane * 8 + 4];
    double best = -1e300; int bestc = 0x7fffffff;
    const bool all = (cnt > 7) || (cnt <= 0);   // overflow fallback: recheck every class
    const int ncand = all ? N_C : cnt;
    for (int s = 0; s < ncand; ++s) {
        const int c = all ? s : candG[(size_t)row * 8 + 1 + s];
        const float* wc = W + (size_t)c * N_F + lane * 8;
        const float4 w0 = *(const float4*)&wc[0];
        const float4 w1 = *(const float4*)&wc[4];
        double p = (double)x0.x * w0.x + (double)x0.y * w0.y
                 + (double)x0.z * w0.z + (double)x0.w * w0.w
                 + (double)x1.x * w1.x + (double)x1.y * w1.y
                 + (double)x1.z * w1.z + (double)x1.w * w1.w;
        #pragma unroll
        for (int off = 1; off < 64; off <<= 1) p += __shfl_xor(p, off, 64);
        p += (double)b[c];
        if (p > best || (p == best && c < bestc)) { best = p; bestc = c; }
    }
    if (lane == 0) labels[row] = bestc;
}

// ---------------- Phase 2: per-class gather (no atomics): counts, similarity, weight -
__global__ __launch_bounds__(256) void scatter_kernel(
    const float* __restrict__ x, const int* __restrict__ labels,
    const float* __restrict__ sim_init, const float* __restrict__ cnt_init,
    float* __restrict__ out_counts, float* __restrict__ out_sim,
    float* __restrict__ out_w, int N)
{
    const int c    = blockIdx.x;
    const int t    = threadIdx.x;
    const int w    = t >> 6;
    const int lane = t & 63;
    const int fbase = w * 128 + lane * 2;   // this wave's feature slice (float2)

    float acc0 = 0.f, acc1 = 0.f;
    int total = 0;
    for (int base = 0; base < N; base += 256) {
        const int4 l4 = *(const int4*)&labels[base + lane * 4];
        unsigned long long m0 = __ballot(l4.x == c);
        unsigned long long m1 = __ballot(l4.y == c);
        unsigned long long m2 = __ballot(l4.z == c);
        unsigned long long m3 = __ballot(l4.w == c);
        while (m0) { int bit = __ffsll(m0) - 1; m0 &= m0 - 1;
            const float2 v = *(const float2*)&x[(size_t)(base + bit * 4 + 0) * N_F + fbase];
            acc0 += v.x; acc1 += v.y; ++total; }
        while (m1) { int bit = __ffsll(m1) - 1; m1 &= m1 - 1;
            const float2 v = *(const float2*)&x[(size_t)(base + bit * 4 + 1) * N_F + fbase];
            acc0 += v.x; acc1 += v.y; ++total; }
        while (m2) { int bit = __ffsll(m2) - 1; m2 &= m2 - 1;
            const float2 v = *(const float2*)&x[(size_t)(base + bit * 4 + 2) * N_F + fbase];
            acc0 += v.x; acc1 += v.y; ++total; }
        while (m3) { int bit = __ffsll(m3) - 1; m3 &= m3 - 1;
            const float2 v = *(const float2*)&x[(size_t)(base + bit * 4 + 3) * N_F + fbase];
            acc0 += v.x; acc1 += v.y; ++total; }
    }
    const float countf = cnt_init[c] + (float)total;
    if (t == 0) out_counts[c] = countf;
    const float2 si = *(const float2*)&sim_init[(size_t)c * N_F + fbase];
    const float s0 = acc0 + si.x, s1 = acc1 + si.y;
    float2 so; so.x = s0; so.y = s1;
    *(float2*)&out_sim[(size_t)c * N_F + fbase] = so;
    float2 wo; wo.x = s0 / countf; wo.y = s1 / countf;
    *(float2*)&out_w[(size_t)c * N_F + fbase] = wo;
}

extern "C" void kernel_launch(void* const* d_in, const int* in_sizes, int n_in,
                              void* d_out, int out_size, void* d_ws, size_t ws_size,
                              hipStream_t stream) {
    const float* x        = (const float*)d_in[0];
    const float* W        = (const float*)d_in[1];
    const float* b        = (const float*)d_in[2];
    const float* sim_init = (const float*)d_in[3];
    const float* cnt_init = (const float*)d_in[4];
    const int N = in_sizes[0] / N_F;   // 131072

    float* out_att    = (float*)d_out;
    float* out_counts = out_att + (size_t)N * N_F;
    float* out_sim    = out_counts + N_C;
    float* out_w      = out_sim + (size_t)N_C * N_F;

    int* labels = (int*)d_ws;          // N ints
    int* candG  = labels + N;          // N*8 ints (cnt + up to 7 candidate classes)

    gemm_argmax_kernel<<<N / BM, 256, 0, stream>>>(x, W, b, out_att, candG);
    label_kernel<<<N / 4, 256, 0, stream>>>(x, W, b, candG, labels);
    scatter_kernel<<<N_C, 256, 0, stream>>>(x, labels, sim_init, cnt_init,
                                            out_counts, out_sim, out_w, N);
}